// Round 8
// baseline (648.522 us; speedup 1.0000x reference)
//
#include <hip/hip_runtime.h>
#include <math.h>

#define BSZ 4
#define Lseq 2048
#define DM 64
#define ED 128
#define NST 32
#define DCONVK 16
#define NLAYERS 4
#define DTRANK 4
#define EPSV 1e-5f
#define NC 64                 // chunks along L for the scan
#define LC (Lseq / NC)        // 32 steps per chunk
#define TT 32                 // tokens per block in k_layer_gemm
#define CS_TOK 32             // tokens per block in k_conv_scan (== LC)

__device__ __forceinline__ float sigf(float x) { return 1.0f / (1.0f + __expf(-x)); }
__device__ __forceinline__ float hsum4(float4 a) { return (a.x + a.y) + (a.z + a.w); }

// ---------------- K_A: [outproj(prev y) + residual] + rmsnorm + inproj, 32 tokens/block
__global__ __launch_bounds__(256) void k_layer_gemm(
    const float* __restrict__ y, const float* __restrict__ ow,
    const float* __restrict__ ob, const float* __restrict__ hin,
    const float* __restrict__ norm_w, const float* __restrict__ in_w,
    const float* __restrict__ in_b, float* __restrict__ hout,
    float* __restrict__ xin, float* __restrict__ zb, int has_out)
{
    const int t0 = blockIdx.x * TT;
    const int tid = threadIdx.x;
    const int lane = tid & 63;
    const int wv = tid >> 6;              // wave 0..3 -> tokens [wv*8, wv*8+8)
    __shared__ __align__(16) float ys[TT][ED];   // 16 KB
    __shared__ __align__(16) float hn[TT][DM];   //  8 KB

    float hval[8];
    const float nw = norm_w[lane];

    if (has_out) {
        {
            const float4* src = (const float4*)(y + (size_t)t0 * ED);
            float4* dst = (float4*)&ys[0][0];
            #pragma unroll
            for (int i = 0; i < (TT * ED / 4) / 256; ++i)   // 4
                dst[tid + i * 256] = src[tid + i * 256];
        }
        __syncthreads();
        // outproj: thread owns d=lane, 8 tokens; acc held across both k-passes
        float4 acc[8];
        #pragma unroll
        for (int j = 0; j < 8; ++j) acc[j] = make_float4(0.f, 0.f, 0.f, 0.f);
        #pragma unroll
        for (int p = 0; p < 2; ++p) {
            float4 w4[16];
            const float4* wr = (const float4*)(ow + lane * ED + p * 64);
            #pragma unroll
            for (int i = 0; i < 16; ++i) w4[i] = wr[i];
            #pragma unroll
            for (int j = 0; j < 8; ++j) {
                const float4* yv = (const float4*)&ys[wv * 8 + j][p * 64];
                #pragma unroll
                for (int i = 0; i < 16; ++i) {
                    float4 hv = yv[i];
                    acc[j].x = fmaf(hv.x, w4[i].x, acc[j].x);
                    acc[j].y = fmaf(hv.y, w4[i].y, acc[j].y);
                    acc[j].z = fmaf(hv.z, w4[i].z, acc[j].z);
                    acc[j].w = fmaf(hv.w, w4[i].w, acc[j].w);
                }
            }
        }
        const float obd = ob[lane];
        #pragma unroll
        for (int j = 0; j < 8; ++j) {
            const int tok = t0 + wv * 8 + j;
            hval[j] = hsum4(acc[j]) + obd + hin[(size_t)tok * DM + lane];
            hout[(size_t)tok * DM + lane] = hval[j];
        }
    } else {
        #pragma unroll
        for (int j = 0; j < 8; ++j)
            hval[j] = hin[(size_t)(t0 + wv * 8 + j) * DM + lane];
    }

    // rmsnorm (lane = d, butterfly over 64 lanes)
    #pragma unroll
    for (int j = 0; j < 8; ++j) {
        float ss = hval[j] * hval[j];
        #pragma unroll
        for (int off = 32; off; off >>= 1) ss += __shfl_xor(ss, off, 64);
        const float sc = rsqrtf(ss * (1.0f / DM) + EPSV);
        hn[wv * 8 + j][lane] = hval[j] * sc * nw;
    }
    __syncthreads();

    // inproj: thread owns output channel tid (0..255), loops 32 tokens, w in regs once
    {
        float4 w4[16];
        const float4* wr = (const float4*)(in_w + tid * DM);
        #pragma unroll
        for (int i = 0; i < 16; ++i) w4[i] = wr[i];
        const float bias = in_b[tid];
        #pragma unroll 4
        for (int tok = 0; tok < TT; ++tok) {
            const float4* hv4 = (const float4*)&hn[tok][0];
            float4 a4 = make_float4(0.f, 0.f, 0.f, 0.f);
            #pragma unroll
            for (int i = 0; i < 16; ++i) {
                float4 hv = hv4[i];
                a4.x = fmaf(hv.x, w4[i].x, a4.x);
                a4.y = fmaf(hv.y, w4[i].y, a4.y);
                a4.z = fmaf(hv.z, w4[i].z, a4.z);
                a4.w = fmaf(hv.w, w4[i].w, a4.w);
            }
            const float r = bias + hsum4(a4);
            if (tid < ED) xin[(size_t)(t0 + tok) * ED + tid] = r;
            else          zb[(size_t)(t0 + tok) * ED + (tid - ED)] = r;
        }
    }
}

// ---------------- K_B: conv + silu + xproj + dtproj + LOCAL SCAN, one chunk (32 tokens)/block
__global__ __launch_bounds__(256) void k_conv_scan(
    const float* __restrict__ xin, const float* __restrict__ conv_w,
    const float* __restrict__ conv_b, const float* __restrict__ xproj_w,
    const float* __restrict__ dtproj_w, const float* __restrict__ dtproj_b,
    const float* __restrict__ A_log,
    float* __restrict__ xc_out, float* __restrict__ delta_out,
    float* __restrict__ Bout, float* __restrict__ Cout,
    float* __restrict__ aprod, float* __restrict__ hloc)
{
    const int blk = blockIdx.x;             // BSZ * NC = 256 blocks
    const int b   = blk >> 6;
    const int c   = blk & 63;               // chunk index
    const int l0  = c * CS_TOK;
    const size_t t0 = (size_t)b * Lseq + l0;
    const int tid = threadIdx.x;
    __shared__ __align__(16) float xs[(CS_TOK + DCONVK - 1) * ED];  // 47 rows, 24 KB
    __shared__ __align__(16) float xcs[CS_TOK][ED];                  // 16 KB
    __shared__ __align__(16) float dl[CS_TOK][ED];                   // 16 KB (delta)
    __shared__ __align__(16) float Bs[CS_TOK][NST];                  //  4 KB
    __shared__ float dts[CS_TOK][DTRANK];

    // stage xin rows (float4 coalesced, zero-fill before sequence start)
    {
        const int NV = (CS_TOK + DCONVK - 1) * ED / 4;   // 1504
        for (int idx4 = tid; idx4 < NV; idx4 += 256) {
            const int row = idx4 >> 5;
            const int lrow = l0 - (DCONVK - 1) + row;
            float4 v = make_float4(0.f, 0.f, 0.f, 0.f);
            if (lrow >= 0)
                v = ((const float4*)(xin + ((size_t)b * Lseq + lrow) * ED))[idx4 & 31];
            ((float4*)xs)[idx4] = v;
        }
    }
    __syncthreads();

    const int e = tid & 127, half = tid >> 7;   // half -> tokens [half*16, half*16+16)
    // conv + silu
    {
        float w[DCONVK];
        {
            const float4* cw = (const float4*)(conv_w + e * DCONVK);
            #pragma unroll
            for (int i = 0; i < 4; ++i) {
                float4 cc = cw[i];
                w[i*4+0] = cc.x; w[i*4+1] = cc.y; w[i*4+2] = cc.z; w[i*4+3] = cc.w;
            }
        }
        const float cb = conv_b[e];
        #pragma unroll
        for (int j = 0; j < 16; ++j) {
            const int tok = half * 16 + j;
            float acc = cb;
            #pragma unroll
            for (int k = 0; k < DCONVK; ++k)
                acc = fmaf(xs[(tok + k) * ED + e], w[k], acc);
            const float xcv = acc * sigf(acc);
            xcs[tok][e] = xcv;
            xc_out[(t0 + tok) * ED + e] = xcv;
        }
    }
    __syncthreads();

    // xproj: wave wv -> tokens [wv*8, wv*8+8); lane = dbc row 0..63 (primary)
    {
        const int wv = tid >> 6, lane = tid & 63;
        float4 acc[8];
        #pragma unroll
        for (int j = 0; j < 8; ++j) acc[j] = make_float4(0.f, 0.f, 0.f, 0.f);
        #pragma unroll
        for (int p = 0; p < 2; ++p) {
            float4 w4[16];
            const float4* wr = (const float4*)(xproj_w + lane * ED + p * 64);
            #pragma unroll
            for (int i = 0; i < 16; ++i) w4[i] = wr[i];
            #pragma unroll
            for (int j = 0; j < 8; ++j) {
                const float4* yv = (const float4*)&xcs[wv * 8 + j][p * 64];
                #pragma unroll
                for (int i = 0; i < 16; ++i) {
                    float4 hv = yv[i];
                    acc[j].x = fmaf(hv.x, w4[i].x, acc[j].x);
                    acc[j].y = fmaf(hv.y, w4[i].y, acc[j].y);
                    acc[j].z = fmaf(hv.z, w4[i].z, acc[j].z);
                    acc[j].w = fmaf(hv.w, w4[i].w, acc[j].w);
                }
            }
        }
        #pragma unroll
        for (int j = 0; j < 8; ++j) {
            const int tok = wv * 8 + j;
            const float v = hsum4(acc[j]);
            if (lane < DTRANK) {
                dts[tok][lane] = v;
            } else if (lane < DTRANK + NST) {
                Bs[tok][lane - DTRANK] = v;
                Bout[(t0 + tok) * NST + (lane - DTRANK)] = v;
            } else {
                Cout[(t0 + tok) * NST + (lane - DTRANK - NST)] = v;
            }
        }
        // leftover rows 64..67 (C idx 28..31): lane = 8*tsub + 2*ridx + ks
        {
            const int tsub = lane >> 3;            // 0..7
            const int ridx = (lane >> 1) & 3;      // 0..3
            const int ks   = lane & 1;             // k-half
            const int r4   = 64 + ridx;
            const int tok  = wv * 8 + tsub;
            const float4* wr = (const float4*)(xproj_w + r4 * ED + ks * 64);
            const float4* yv = (const float4*)&xcs[tok][ks * 64];
            float4 a4 = make_float4(0.f, 0.f, 0.f, 0.f);
            #pragma unroll
            for (int i = 0; i < 16; ++i) {
                float4 hv = yv[i]; float4 wv4 = wr[i];
                a4.x = fmaf(hv.x, wv4.x, a4.x);
                a4.y = fmaf(hv.y, wv4.y, a4.y);
                a4.z = fmaf(hv.z, wv4.z, a4.z);
                a4.w = fmaf(hv.w, wv4.w, a4.w);
            }
            float v = hsum4(a4);
            v += __shfl_xor(v, 1, 64);
            if (ks == 0) Cout[(t0 + tok) * NST + (r4 - DTRANK - NST)] = v;
        }
    }
    __syncthreads();

    // dtproj + softplus -> dl (LDS) + delta_out (global)
    {
        const float4 dwv = *(const float4*)(dtproj_w + e * DTRANK);
        const float bias = dtproj_b[e];
        #pragma unroll
        for (int j = 0; j < 16; ++j) {
            const int tok = half * 16 + j;
            float a = bias;
            a = fmaf(dts[tok][0], dwv.x, a);
            a = fmaf(dts[tok][1], dwv.y, a);
            a = fmaf(dts[tok][2], dwv.z, a);
            a = fmaf(dts[tok][3], dwv.w, a);
            const float sp = fmaxf(a, 0.f) + log1pf(__expf(-fabsf(a)));
            dl[tok][e] = sp;
            delta_out[(t0 + tok) * ED + e] = sp;
        }
    }
    __syncthreads();

    // local scan from LDS: thread owns (e = tid&127, n in [half*16, half*16+16))
    {
        const int se = e;
        const int n0 = half * 16;
        float Aen[16];
        {
            const float4* ap4 = (const float4*)(A_log + se * NST + n0);
            #pragma unroll
            for (int i = 0; i < 4; ++i) {
                float4 v = ap4[i];
                Aen[i*4+0] = -__expf(v.x); Aen[i*4+1] = -__expf(v.y);
                Aen[i*4+2] = -__expf(v.z); Aen[i*4+3] = -__expf(v.w);
            }
        }
        float hs[16];
        #pragma unroll
        for (int k = 0; k < 16; ++k) hs[k] = 0.f;
        float dsum = 0.f;
        for (int l = 0; l < CS_TOK; ++l) {
            const float de  = dl[l][se];
            const float xce = xcs[l][se];
            const float dexc = de * xce;
            dsum += de;
            const float4* B4p = (const float4*)&Bs[l][n0];
            #pragma unroll
            for (int i = 0; i < 4; ++i) {
                const float4 B4 = B4p[i];
                float a;
                a = __expf(de * Aen[i*4+0]); hs[i*4+0] = fmaf(a, hs[i*4+0], B4.x * dexc);
                a = __expf(de * Aen[i*4+1]); hs[i*4+1] = fmaf(a, hs[i*4+1], B4.y * dexc);
                a = __expf(de * Aen[i*4+2]); hs[i*4+2] = fmaf(a, hs[i*4+2], B4.z * dexc);
                a = __expf(de * Aen[i*4+3]); hs[i*4+3] = fmaf(a, hs[i*4+3], B4.w * dexc);
            }
        }
        const size_t idx = (((size_t)b * NC + c) * ED + se) * NST + n0;
        #pragma unroll
        for (int i = 0; i < 4; ++i) {
            *(float4*)(hloc + idx + i * 4) =
                make_float4(hs[i*4+0], hs[i*4+1], hs[i*4+2], hs[i*4+3]);
            *(float4*)(aprod + idx + i * 4) =
                make_float4(__expf(Aen[i*4+0] * dsum), __expf(Aen[i*4+1] * dsum),
                            __expf(Aen[i*4+2] * dsum), __expf(Aen[i*4+3] * dsum));
        }
    }
}

// ---------------- K3b (every layer): chunk combine. Rewrites hloc in place into the
// per-chunk INITIAL states; also emits final state hend (used by last layer).
__global__ __launch_bounds__(256) void k_scan_combine(
    const float* __restrict__ aprod, float* __restrict__ hloc,
    float* __restrict__ hend)
{
    const int tid = blockIdx.x * 256 + threadIdx.x;   // 0..16383
    const int b = tid >> 12;                          // ED*NST = 4096
    const int en = tid & 4095;
    size_t idx = (size_t)b * NC * (ED * NST) + en;
    float h = 0.f;
    #pragma unroll 4
    for (int c = 0; c < NC; ++c) {
        const float a = aprod[idx];
        const float u = hloc[idx];
        hloc[idx] = h;                 // initial state for chunk c
        h = fmaf(a, h, u);
        idx += ED * NST;
    }
    hend[(size_t)b * (ED * NST) + en] = h;
}

// ---------------- K3c: per-chunk scan from hinit (uniform work), emit y.
__global__ __launch_bounds__(256) void k_scan_y(
    const float* __restrict__ delta, const float* __restrict__ Bv,
    const float* __restrict__ Cv, const float* __restrict__ xc,
    const float* __restrict__ zb, const float* __restrict__ A_log,
    const float* __restrict__ Dp, const float* __restrict__ hinit,
    float* __restrict__ y)
{
    const int b = blockIdx.z;
    const int c = blockIdx.x;
    const int lane = threadIdx.x & 63;
    const int wv = threadIdx.x >> 6;
    const int e = blockIdx.y * 32 + wv * 8 + (lane >> 3);
    const int nlane = lane & 7;
    const int n0 = nlane * 4;

    const float4 al4 = *(const float4*)(A_log + e * NST + n0);
    float Aen[4] = { -__expf(al4.x), -__expf(al4.y), -__expf(al4.z), -__expf(al4.w) };
    const float dpe = Dp[e];

    float hs[4];
    {
        const float4 h4 = *(const float4*)(hinit + (((size_t)b * NC + c) * ED + e) * NST + n0);
        hs[0] = h4.x; hs[1] = h4.y; hs[2] = h4.z; hs[3] = h4.w;
    }

    const size_t base = (size_t)b * Lseq + (size_t)c * LC;
    #pragma unroll 2
    for (int l = 0; l < LC; ++l) {
        const size_t tok = base + l;
        const float de  = delta[tok * ED + e];
        const float xce = xc[tok * ED + e];
        const float4 B4 = *(const float4*)(Bv + tok * NST + n0);
        const float4 C4 = *(const float4*)(Cv + tok * NST + n0);
        const float dexc = de * xce;
        float a;
        a = __expf(de * Aen[0]); hs[0] = fmaf(a, hs[0], B4.x * dexc);
        a = __expf(de * Aen[1]); hs[1] = fmaf(a, hs[1], B4.y * dexc);
        a = __expf(de * Aen[2]); hs[2] = fmaf(a, hs[2], B4.z * dexc);
        a = __expf(de * Aen[3]); hs[3] = fmaf(a, hs[3], B4.w * dexc);
        float p = hs[0] * C4.x;
        p = fmaf(hs[1], C4.y, p);
        p = fmaf(hs[2], C4.z, p);
        p = fmaf(hs[3], C4.w, p);
        p += __shfl_xor(p, 1, 64);
        p += __shfl_xor(p, 2, 64);
        p += __shfl_xor(p, 4, 64);
        if (nlane == 0) {
            const float zi = zb[tok * ED + e];
            y[tok * ED + e] = (p + dpe * xce) * (zi * sigf(zi));
        }
    }
}

// ---------------- K5: last layer head: y(L-1) from hend, then fc dot -> logits
__global__ __launch_bounds__(128) void k_final_last(
    const float* __restrict__ hend, const float* __restrict__ Cv,
    const float* __restrict__ xc, const float* __restrict__ zb,
    const float* __restrict__ Dp, const float* __restrict__ fcw,
    const float* __restrict__ fcb, float* __restrict__ out)
{
    const int b = blockIdx.x;
    const int e = threadIdx.x;       // 0..127
    const size_t tok = (size_t)b * Lseq + (Lseq - 1);
    const float* hp = hend + (size_t)b * (ED * NST) + e * NST;
    const float* cp = Cv + tok * NST;
    float p = 0.f;
    #pragma unroll
    for (int n = 0; n < NST; ++n) p = fmaf(hp[n], cp[n], p);
    const float xce = xc[tok * ED + e];
    const float zi  = zb[tok * ED + e];
    float val = (p + Dp[e] * xce) * (zi * sigf(zi)) * fcw[e];
    __shared__ float sred[2];
    #pragma unroll
    for (int off = 32; off; off >>= 1) val += __shfl_xor(val, off, 64);
    if ((threadIdx.x & 63) == 0) sred[threadIdx.x >> 6] = val;
    __syncthreads();
    if (threadIdx.x == 0) out[b] = sred[0] + sred[1] + fcb[0];
}

extern "C" void kernel_launch(void* const* d_in, const int* in_sizes, int n_in,
                              void* d_out, int out_size, void* d_ws, size_t ws_size,
                              hipStream_t stream)
{
    const float* x         = (const float*)d_in[0];
    const float* in_w      = (const float*)d_in[1];
    const float* in_b      = (const float*)d_in[2];
    const float* conv_w    = (const float*)d_in[3];
    const float* conv_b    = (const float*)d_in[4];
    const float* xproj_w   = (const float*)d_in[5];
    const float* dtproj_w  = (const float*)d_in[6];
    const float* dtproj_b  = (const float*)d_in[7];
    const float* A_log     = (const float*)d_in[8];
    const float* Dp        = (const float*)d_in[9];
    const float* outproj_w = (const float*)d_in[10];
    const float* outproj_b = (const float*)d_in[11];
    const float* norm_w    = (const float*)d_in[12];
    const float* fc_w      = (const float*)d_in[13];
    const float* fc_b      = (const float*)d_in[14];

    const size_t TOK = (size_t)BSZ * Lseq;
    float* ws = (float*)d_ws;
    float* h0    = ws; ws += TOK * DM;
    float* h1    = ws; ws += TOK * DM;
    float* xin   = ws; ws += TOK * ED;   // reused as y after the scan
    float* zbuf  = ws; ws += TOK * ED;
    float* xc    = ws; ws += TOK * ED;
    float* dlt   = ws; ws += TOK * ED;
    float* Bv    = ws; ws += TOK * NST;
    float* Cv    = ws; ws += TOK * NST;
    float* aprod = ws; ws += (size_t)BSZ * NC * ED * NST;
    float* hloc  = ws; ws += (size_t)BSZ * NC * ED * NST;   // becomes hinit in-place
    float* hend  = ws; ws += (size_t)BSZ * ED * NST;

    const float* hres = x;               // residual stream input for current layer
    float* hbufs[2] = { h0, h1 };

    for (int i = 0; i < NLAYERS; ++i) {
        const int last = (i == NLAYERS - 1);
        if (i == 0) {
            k_layer_gemm<<<(int)(TOK / TT), 256, 0, stream>>>(
                nullptr, nullptr, nullptr, x, norm_w, in_w, in_b,
                nullptr, xin, zbuf, 0);
        } else {
            float* hout = hbufs[i & 1];
            k_layer_gemm<<<(int)(TOK / TT), 256, 0, stream>>>(
                xin /* y of prev layer */,
                outproj_w + (size_t)(i - 1) * DM * ED,
                outproj_b + (size_t)(i - 1) * DM,
                hres, norm_w + (size_t)i * DM,
                in_w + (size_t)i * 2 * ED * DM, in_b + (size_t)i * 2 * ED,
                hout, xin, zbuf, 1);
            hres = hout;
        }
        const float* Alog_i = A_log + (size_t)i * ED * NST;
        k_conv_scan<<<(int)(BSZ * NC), 256, 0, stream>>>(
            xin, conv_w + (size_t)i * ED * DCONVK, conv_b + (size_t)i * ED,
            xproj_w + (size_t)i * (DTRANK + 2 * NST) * ED,
            dtproj_w + (size_t)i * ED * DTRANK, dtproj_b + (size_t)i * ED,
            Alog_i, xc, dlt, Bv, Cv, aprod, hloc);
        k_scan_combine<<<(BSZ * ED * NST) / 256, 256, 0, stream>>>(
            aprod, hloc, hend);
        if (!last) {
            k_scan_y<<<dim3(NC, ED / 32, BSZ), 256, 0, stream>>>(
                dlt, Bv, Cv, xc, zbuf, Alog_i, Dp + (size_t)i * ED,
                hloc, xin);
        } else {
            k_final_last<<<BSZ, 128, 0, stream>>>(
                hend, Cv, xc, zbuf, Dp + (size_t)i * ED, fc_w, fc_b, (float*)d_out);
        }
    }
}

// Round 9
// 466.549 us; speedup vs baseline: 1.3900x; 1.3900x over previous
//
#include <hip/hip_runtime.h>
#include <math.h>

#define BSZ 4
#define Lseq 2048
#define DM 64
#define ED 128
#define NST 32
#define DCONVK 16
#define NLAYERS 4
#define DTRANK 4
#define EPSV 1e-5f
#define NC 128                // chunks along L (chunk == conv tile)
#define LC (Lseq / NC)        // 16 steps per chunk
#define TT 16                 // tokens per block in k_layer_gemm
#define TT2 16                // tokens per block in k_conv_scan (== LC)

__device__ __forceinline__ float sigf(float x) { return 1.0f / (1.0f + __expf(-x)); }
__device__ __forceinline__ float hsum4(float4 a) { return (a.x + a.y) + (a.z + a.w); }

// ---------------- K_A: [outproj(prev y) + residual] + rmsnorm + inproj, 16 tokens/block
__global__ __launch_bounds__(256) void k_layer_gemm(
    const float* __restrict__ y, const float* __restrict__ ow,
    const float* __restrict__ ob, const float* __restrict__ hin,
    const float* __restrict__ norm_w, const float* __restrict__ in_w,
    const float* __restrict__ in_b, float* __restrict__ hout,
    float* __restrict__ xin, float* __restrict__ zb, int has_out)
{
    const int t0 = blockIdx.x * TT;
    const int tid = threadIdx.x;
    const int lane = tid & 63;
    const int wv = tid >> 6;              // wave 0..3 -> tokens [wv*4, wv*4+4)
    __shared__ __align__(16) float ys[TT][ED];
    __shared__ __align__(16) float hn[TT][DM];

    float hval[4];
    const float nw = norm_w[lane];

    if (has_out) {
        {
            const float4* src = (const float4*)(y + (size_t)t0 * ED);
            float4* dst = (float4*)&ys[0][0];
            #pragma unroll
            for (int i = 0; i < (TT * ED / 4) / 256; ++i)
                dst[tid + i * 256] = src[tid + i * 256];
        }
        __syncthreads();
        float4 acc[4];
        #pragma unroll
        for (int j = 0; j < 4; ++j) acc[j] = make_float4(0.f, 0.f, 0.f, 0.f);
        #pragma unroll
        for (int p = 0; p < 2; ++p) {
            float4 w4[16];
            const float4* wr = (const float4*)(ow + lane * ED + p * 64);
            #pragma unroll
            for (int i = 0; i < 16; ++i) w4[i] = wr[i];
            #pragma unroll
            for (int j = 0; j < 4; ++j) {
                const float4* yv = (const float4*)&ys[wv * 4 + j][p * 64];
                #pragma unroll
                for (int i = 0; i < 16; ++i) {
                    float4 hv = yv[i];
                    acc[j].x = fmaf(hv.x, w4[i].x, acc[j].x);
                    acc[j].y = fmaf(hv.y, w4[i].y, acc[j].y);
                    acc[j].z = fmaf(hv.z, w4[i].z, acc[j].z);
                    acc[j].w = fmaf(hv.w, w4[i].w, acc[j].w);
                }
            }
        }
        const float obd = ob[lane];
        #pragma unroll
        for (int j = 0; j < 4; ++j) {
            const int tok = t0 + wv * 4 + j;
            hval[j] = hsum4(acc[j]) + obd + hin[(size_t)tok * DM + lane];
            hout[(size_t)tok * DM + lane] = hval[j];
        }
    } else {
        #pragma unroll
        for (int j = 0; j < 4; ++j)
            hval[j] = hin[(size_t)(t0 + wv * 4 + j) * DM + lane];
    }

    #pragma unroll
    for (int j = 0; j < 4; ++j) {
        float ss = hval[j] * hval[j];
        #pragma unroll
        for (int off = 32; off; off >>= 1) ss += __shfl_xor(ss, off, 64);
        const float sc = rsqrtf(ss * (1.0f / DM) + EPSV);
        hn[wv * 4 + j][lane] = hval[j] * sc * nw;
    }
    __syncthreads();

    {
        float4 w4[16];
        const float4* wr = (const float4*)(in_w + tid * DM);
        #pragma unroll
        for (int i = 0; i < 16; ++i) w4[i] = wr[i];
        const float bias = in_b[tid];
        #pragma unroll 4
        for (int tok = 0; tok < TT; ++tok) {
            const float4* hv4 = (const float4*)&hn[tok][0];
            float4 a4 = make_float4(0.f, 0.f, 0.f, 0.f);
            #pragma unroll
            for (int i = 0; i < 16; ++i) {
                float4 hv = hv4[i];
                a4.x = fmaf(hv.x, w4[i].x, a4.x);
                a4.y = fmaf(hv.y, w4[i].y, a4.y);
                a4.z = fmaf(hv.z, w4[i].z, a4.z);
                a4.w = fmaf(hv.w, w4[i].w, a4.w);
            }
            const float r = bias + hsum4(a4);
            if (tid < ED) xin[(size_t)(t0 + tok) * ED + tid] = r;
            else          zb[(size_t)(t0 + tok) * ED + (tid - ED)] = r;
        }
    }
}

// ---------------- K_B: conv + silu + xproj + dtproj + local scan — 16 tokens (=1 chunk)/block
// Exactly the R7 conv_proj phase structure (proven acc[4] tile, no spill) with a final
// LDS-resident local-scan phase. delta LDS buffer aliases xs (dead after conv).
__global__ __launch_bounds__(256) void k_conv_scan(
    const float* __restrict__ xin, const float* __restrict__ conv_w,
    const float* __restrict__ conv_b, const float* __restrict__ xproj_w,
    const float* __restrict__ dtproj_w, const float* __restrict__ dtproj_b,
    const float* __restrict__ A_log,
    float* __restrict__ xc_out, float* __restrict__ delta_out,
    float* __restrict__ Bout, float* __restrict__ Cout,
    float* __restrict__ aprod, float* __restrict__ hloc)
{
    const int blk = blockIdx.x;             // BSZ * NC = 512 blocks
    const int b   = blk >> 7;               // NC = 128
    const int c   = blk & 127;
    const int l0  = c * TT2;
    const size_t t0 = (size_t)b * Lseq + l0;
    const int tid = threadIdx.x;
    __shared__ __align__(16) float xs[(TT2 + DCONVK - 1) * ED];   // 31 rows, 15.5 KB
    __shared__ __align__(16) float xcs[TT2][ED];                   // 8 KB
    __shared__ __align__(16) float Bs[TT2][NST];                   // 2 KB
    __shared__ float dts[TT2][DTRANK];
    float (*dl)[ED] = (float (*)[ED])xs;    // alias: xs dead after conv phase

    // stage xin rows (float4 coalesced, zero-fill before sequence start)
    {
        const int NV = (TT2 + DCONVK - 1) * ED / 4;   // 992
        for (int idx4 = tid; idx4 < NV; idx4 += 256) {
            const int row = idx4 >> 5;
            const int lrow = l0 - (DCONVK - 1) + row;
            float4 v = make_float4(0.f, 0.f, 0.f, 0.f);
            if (lrow >= 0)
                v = ((const float4*)(xin + ((size_t)b * Lseq + lrow) * ED))[idx4 & 31];
            ((float4*)xs)[idx4] = v;
        }
    }
    __syncthreads();

    const int e = tid & 127, half = tid >> 7;   // half -> tokens [half*8, half*8+8)
    // conv + silu
    {
        float w[DCONVK];
        {
            const float4* cw = (const float4*)(conv_w + e * DCONVK);
            #pragma unroll
            for (int i = 0; i < 4; ++i) {
                float4 cc = cw[i];
                w[i*4+0] = cc.x; w[i*4+1] = cc.y; w[i*4+2] = cc.z; w[i*4+3] = cc.w;
            }
        }
        const float cb = conv_b[e];
        #pragma unroll
        for (int j = 0; j < 8; ++j) {
            const int tok = half * 8 + j;
            float acc = cb;
            #pragma unroll
            for (int k = 0; k < DCONVK; ++k)
                acc = fmaf(xs[(tok + k) * ED + e], w[k], acc);
            const float xcv = acc * sigf(acc);
            xcs[tok][e] = xcv;
            xc_out[(t0 + tok) * ED + e] = xcv;
        }
    }
    __syncthreads();   // xs dead from here on

    // xproj: wave wv -> tokens [wv*4, wv*4+4); lane = dbc row 0..63 (acc[4] proven tile)
    {
        const int wv = tid >> 6, lane = tid & 63;
        float4 acc[4];
        #pragma unroll
        for (int j = 0; j < 4; ++j) acc[j] = make_float4(0.f, 0.f, 0.f, 0.f);
        #pragma unroll
        for (int p = 0; p < 2; ++p) {
            float4 w4[16];
            const float4* wr = (const float4*)(xproj_w + lane * ED + p * 64);
            #pragma unroll
            for (int i = 0; i < 16; ++i) w4[i] = wr[i];
            #pragma unroll
            for (int j = 0; j < 4; ++j) {
                const float4* yv = (const float4*)&xcs[wv * 4 + j][p * 64];
                #pragma unroll
                for (int i = 0; i < 16; ++i) {
                    float4 hv = yv[i];
                    acc[j].x = fmaf(hv.x, w4[i].x, acc[j].x);
                    acc[j].y = fmaf(hv.y, w4[i].y, acc[j].y);
                    acc[j].z = fmaf(hv.z, w4[i].z, acc[j].z);
                    acc[j].w = fmaf(hv.w, w4[i].w, acc[j].w);
                }
            }
        }
        #pragma unroll
        for (int j = 0; j < 4; ++j) {
            const int tok = wv * 4 + j;
            const float v = hsum4(acc[j]);
            if (lane < DTRANK) {
                dts[tok][lane] = v;
            } else if (lane < DTRANK + NST) {
                Bs[tok][lane - DTRANK] = v;
                Bout[(t0 + tok) * NST + (lane - DTRANK)] = v;
            } else {
                Cout[(t0 + tok) * NST + (lane - DTRANK - NST)] = v;
            }
        }
        // leftover rows 64..67 (C idx 28..31): lane = 16*tsub + 4*ks + ridx
        {
            const int ridx = lane & 3;
            const int ks   = (lane >> 2) & 3;
            const int tsub = lane >> 4;
            const int r4   = 64 + ridx;
            const int tok  = wv * 4 + tsub;
            const float4* wr = (const float4*)(xproj_w + r4 * ED + ks * 32);
            const float4* yv = (const float4*)&xcs[tok][ks * 32];
            float4 a4 = make_float4(0.f, 0.f, 0.f, 0.f);
            #pragma unroll
            for (int i = 0; i < 8; ++i) {
                float4 hv = yv[i]; float4 wv4 = wr[i];
                a4.x = fmaf(hv.x, wv4.x, a4.x);
                a4.y = fmaf(hv.y, wv4.y, a4.y);
                a4.z = fmaf(hv.z, wv4.z, a4.z);
                a4.w = fmaf(hv.w, wv4.w, a4.w);
            }
            float v = hsum4(a4);
            v += __shfl_xor(v, 4, 64);
            v += __shfl_xor(v, 8, 64);
            if (ks == 0) Cout[(t0 + tok) * NST + (r4 - DTRANK - NST)] = v;
        }
    }
    __syncthreads();

    // dtproj + softplus -> dl (aliased LDS) + delta_out
    {
        const float4 dwv = *(const float4*)(dtproj_w + e * DTRANK);
        const float bias = dtproj_b[e];
        #pragma unroll
        for (int j = 0; j < 8; ++j) {
            const int tok = half * 8 + j;
            float a = bias;
            a = fmaf(dts[tok][0], dwv.x, a);
            a = fmaf(dts[tok][1], dwv.y, a);
            a = fmaf(dts[tok][2], dwv.z, a);
            a = fmaf(dts[tok][3], dwv.w, a);
            const float sp = fmaxf(a, 0.f) + log1pf(__expf(-fabsf(a)));
            dl[tok][e] = sp;
            delta_out[(t0 + tok) * ED + e] = sp;
        }
    }
    __syncthreads();

    // local scan from LDS: thread owns (e, n in [half*16, half*16+16))
    {
        const int n0 = half * 16;
        float Aen[16];
        {
            const float4* ap4 = (const float4*)(A_log + e * NST + n0);
            #pragma unroll
            for (int i = 0; i < 4; ++i) {
                float4 v = ap4[i];
                Aen[i*4+0] = -__expf(v.x); Aen[i*4+1] = -__expf(v.y);
                Aen[i*4+2] = -__expf(v.z); Aen[i*4+3] = -__expf(v.w);
            }
        }
        float hs[16];
        #pragma unroll
        for (int k = 0; k < 16; ++k) hs[k] = 0.f;
        float dsum = 0.f;
        #pragma unroll 2
        for (int l = 0; l < TT2; ++l) {
            const float de  = dl[l][e];
            const float xce = xcs[l][e];
            const float dexc = de * xce;
            dsum += de;
            const float4* B4p = (const float4*)&Bs[l][n0];
            #pragma unroll
            for (int i = 0; i < 4; ++i) {
                const float4 B4 = B4p[i];
                float a;
                a = __expf(de * Aen[i*4+0]); hs[i*4+0] = fmaf(a, hs[i*4+0], B4.x * dexc);
                a = __expf(de * Aen[i*4+1]); hs[i*4+1] = fmaf(a, hs[i*4+1], B4.y * dexc);
                a = __expf(de * Aen[i*4+2]); hs[i*4+2] = fmaf(a, hs[i*4+2], B4.z * dexc);
                a = __expf(de * Aen[i*4+3]); hs[i*4+3] = fmaf(a, hs[i*4+3], B4.w * dexc);
            }
        }
        const size_t idx = (((size_t)b * NC + c) * ED + e) * NST + n0;
        #pragma unroll
        for (int i = 0; i < 4; ++i) {
            *(float4*)(hloc + idx + i * 4) =
                make_float4(hs[i*4+0], hs[i*4+1], hs[i*4+2], hs[i*4+3]);
            *(float4*)(aprod + idx + i * 4) =
                make_float4(__expf(Aen[i*4+0] * dsum), __expf(Aen[i*4+1] * dsum),
                            __expf(Aen[i*4+2] * dsum), __expf(Aen[i*4+3] * dsum));
        }
    }
}

// ---------------- K3b (every layer): chunk combine. Rewrites hloc in place into the
// per-chunk INITIAL states; also emits final state hend (used by last layer).
__global__ __launch_bounds__(256) void k_scan_combine(
    const float* __restrict__ aprod, float* __restrict__ hloc,
    float* __restrict__ hend)
{
    const int tid = blockIdx.x * 256 + threadIdx.x;   // 0..16383
    const int b = tid >> 12;                          // ED*NST = 4096
    const int en = tid & 4095;
    size_t idx = (size_t)b * NC * (ED * NST) + en;
    float h = 0.f;
    #pragma unroll 4
    for (int c = 0; c < NC; ++c) {
        const float a = aprod[idx];
        const float u = hloc[idx];
        hloc[idx] = h;                 // initial state for chunk c
        h = fmaf(a, h, u);
        idx += ED * NST;
    }
    hend[(size_t)b * (ED * NST) + en] = h;
}

// ---------------- K3c: per-chunk scan from hinit (uniform 16-step work), emit y.
__global__ __launch_bounds__(256) void k_scan_y(
    const float* __restrict__ delta, const float* __restrict__ Bv,
    const float* __restrict__ Cv, const float* __restrict__ xc,
    const float* __restrict__ zb, const float* __restrict__ A_log,
    const float* __restrict__ Dp, const float* __restrict__ hinit,
    float* __restrict__ y)
{
    const int b = blockIdx.z;
    const int c = blockIdx.x;
    const int lane = threadIdx.x & 63;
    const int wv = threadIdx.x >> 6;
    const int e = blockIdx.y * 32 + wv * 8 + (lane >> 3);
    const int nlane = lane & 7;
    const int n0 = nlane * 4;

    const float4 al4 = *(const float4*)(A_log + e * NST + n0);
    float Aen[4] = { -__expf(al4.x), -__expf(al4.y), -__expf(al4.z), -__expf(al4.w) };
    const float dpe = Dp[e];

    float hs[4];
    {
        const float4 h4 = *(const float4*)(hinit + (((size_t)b * NC + c) * ED + e) * NST + n0);
        hs[0] = h4.x; hs[1] = h4.y; hs[2] = h4.z; hs[3] = h4.w;
    }

    const size_t base = (size_t)b * Lseq + (size_t)c * LC;
    #pragma unroll 4
    for (int l = 0; l < LC; ++l) {
        const size_t tok = base + l;
        const float de  = delta[tok * ED + e];
        const float xce = xc[tok * ED + e];
        const float4 B4 = *(const float4*)(Bv + tok * NST + n0);
        const float4 C4 = *(const float4*)(Cv + tok * NST + n0);
        const float dexc = de * xce;
        float a;
        a = __expf(de * Aen[0]); hs[0] = fmaf(a, hs[0], B4.x * dexc);
        a = __expf(de * Aen[1]); hs[1] = fmaf(a, hs[1], B4.y * dexc);
        a = __expf(de * Aen[2]); hs[2] = fmaf(a, hs[2], B4.z * dexc);
        a = __expf(de * Aen[3]); hs[3] = fmaf(a, hs[3], B4.w * dexc);
        float p = hs[0] * C4.x;
        p = fmaf(hs[1], C4.y, p);
        p = fmaf(hs[2], C4.z, p);
        p = fmaf(hs[3], C4.w, p);
        p += __shfl_xor(p, 1, 64);
        p += __shfl_xor(p, 2, 64);
        p += __shfl_xor(p, 4, 64);
        if (nlane == 0) {
            const float zi = zb[tok * ED + e];
            y[tok * ED + e] = (p + dpe * xce) * (zi * sigf(zi));
        }
    }
}

// ---------------- K5: last layer head: y(L-1) from hend, then fc dot -> logits
__global__ __launch_bounds__(128) void k_final_last(
    const float* __restrict__ hend, const float* __restrict__ Cv,
    const float* __restrict__ xc, const float* __restrict__ zb,
    const float* __restrict__ Dp, const float* __restrict__ fcw,
    const float* __restrict__ fcb, float* __restrict__ out)
{
    const int b = blockIdx.x;
    const int e = threadIdx.x;       // 0..127
    const size_t tok = (size_t)b * Lseq + (Lseq - 1);
    const float* hp = hend + (size_t)b * (ED * NST) + e * NST;
    const float* cp = Cv + tok * NST;
    float p = 0.f;
    #pragma unroll
    for (int n = 0; n < NST; ++n) p = fmaf(hp[n], cp[n], p);
    const float xce = xc[tok * ED + e];
    const float zi  = zb[tok * ED + e];
    float val = (p + Dp[e] * xce) * (zi * sigf(zi)) * fcw[e];
    __shared__ float sred[2];
    #pragma unroll
    for (int off = 32; off; off >>= 1) val += __shfl_xor(val, off, 64);
    if ((threadIdx.x & 63) == 0) sred[threadIdx.x >> 6] = val;
    __syncthreads();
    if (threadIdx.x == 0) out[b] = sred[0] + sred[1] + fcb[0];
}

extern "C" void kernel_launch(void* const* d_in, const int* in_sizes, int n_in,
                              void* d_out, int out_size, void* d_ws, size_t ws_size,
                              hipStream_t stream)
{
    const float* x         = (const float*)d_in[0];
    const float* in_w      = (const float*)d_in[1];
    const float* in_b      = (const float*)d_in[2];
    const float* conv_w    = (const float*)d_in[3];
    const float* conv_b    = (const float*)d_in[4];
    const float* xproj_w   = (const float*)d_in[5];
    const float* dtproj_w  = (const float*)d_in[6];
    const float* dtproj_b  = (const float*)d_in[7];
    const float* A_log     = (const float*)d_in[8];
    const float* Dp        = (const float*)d_in[9];
    const float* outproj_w = (const float*)d_in[10];
    const float* outproj_b = (const float*)d_in[11];
    const float* norm_w    = (const float*)d_in[12];
    const float* fc_w      = (const float*)d_in[13];
    const float* fc_b      = (const float*)d_in[14];

    const size_t TOK = (size_t)BSZ * Lseq;
    float* ws = (float*)d_ws;
    float* h0    = ws; ws += TOK * DM;
    float* h1    = ws; ws += TOK * DM;
    float* xin   = ws; ws += TOK * ED;   // reused as y after the scan
    float* zbuf  = ws; ws += TOK * ED;
    float* xc    = ws; ws += TOK * ED;
    float* dlt   = ws; ws += TOK * ED;
    float* Bv    = ws; ws += TOK * NST;
    float* Cv    = ws; ws += TOK * NST;
    float* aprod = ws; ws += (size_t)BSZ * NC * ED * NST;   // 8 MB
    float* hloc  = ws; ws += (size_t)BSZ * NC * ED * NST;   // 8 MB, becomes hinit
    float* hend  = ws; ws += (size_t)BSZ * ED * NST;

    const float* hres = x;               // residual stream input for current layer
    float* hbufs[2] = { h0, h1 };

    for (int i = 0; i < NLAYERS; ++i) {
        const int last = (i == NLAYERS - 1);
        if (i == 0) {
            k_layer_gemm<<<(int)(TOK / TT), 256, 0, stream>>>(
                nullptr, nullptr, nullptr, x, norm_w, in_w, in_b,
                nullptr, xin, zbuf, 0);
        } else {
            float* hout = hbufs[i & 1];
            k_layer_gemm<<<(int)(TOK / TT), 256, 0, stream>>>(
                xin /* y of prev layer */,
                outproj_w + (size_t)(i - 1) * DM * ED,
                outproj_b + (size_t)(i - 1) * DM,
                hres, norm_w + (size_t)i * DM,
                in_w + (size_t)i * 2 * ED * DM, in_b + (size_t)i * 2 * ED,
                hout, xin, zbuf, 1);
            hres = hout;
        }
        const float* Alog_i = A_log + (size_t)i * ED * NST;
        k_conv_scan<<<(int)(BSZ * NC), 256, 0, stream>>>(
            xin, conv_w + (size_t)i * ED * DCONVK, conv_b + (size_t)i * ED,
            xproj_w + (size_t)i * (DTRANK + 2 * NST) * ED,
            dtproj_w + (size_t)i * ED * DTRANK, dtproj_b + (size_t)i * ED,
            Alog_i, xc, dlt, Bv, Cv, aprod, hloc);
        k_scan_combine<<<(BSZ * ED * NST) / 256, 256, 0, stream>>>(
            aprod, hloc, hend);
        if (!last) {
            k_scan_y<<<dim3(NC, ED / 32, BSZ), 256, 0, stream>>>(
                dlt, Bv, Cv, xc, zbuf, Alog_i, Dp + (size_t)i * ED,
                hloc, xin);
        } else {
            k_final_last<<<BSZ, 128, 0, stream>>>(
                hend, Cv, xc, zbuf, Dp + (size_t)i * ED, fc_w, fc_b, (float*)d_out);
        }
    }
}